// Round 3
// baseline (873.422 us; speedup 1.0000x reference)
//
#include <hip/hip_runtime.h>

#define BATCH 256
#define TT 4096
#define NS 32
#define NI 8
#define NO 8
#define LCH 16
#define NCH 256   // TT / LCH
#define NSUP 16   // superchunks
#define SLEN 16   // chunks per superchunk

// ws layout (float offsets)
#define WS_M    0                        // 1024
#define WS_N0   1024                     // 256
#define WS_N1   1280                     // 256
#define WS_W    1536                     // 17*256 = 4352
#define WS_PK   5888                     // 17*1024 (ML16^k, k=0..16; [16]=ML256)
#define WS_V    40704                    // BATCH*NCH*NS (v, then reused for r)
#define WS_VV   (40704 + 2097152)        // BATCH*NSUP*NS
#define WS_SS   (40704 + 2097152 + 131072)

__device__ __forceinline__ float dot4(float4 a, float4 b) {
    return a.x * b.x + a.y * b.y + a.z * b.z + a.w * b.w;
}
__device__ __forceinline__ float4 ld4(const float* p) { return *(const float4*)p; }

// ---------------------------------------------------------------------------
// k_pre: build M,N0,N1, W_j, PK[k]=M^16k. All intermediates in LDS; RK stages
// fully unrolled with constexpr tables (no scratch). One block, 1024 threads.
// ---------------------------------------------------------------------------
__global__ __launch_bounds__(1024) void k_pre(const float* __restrict__ tarr,
                                              const float* __restrict__ A,
                                              const float* __restrict__ B,
                                              float* __restrict__ ws) {
    __shared__ float MP[17][1024];  // M^p, p=0..16
    __shared__ float sA[1024];
    __shared__ float Ka[6][1024];
    __shared__ float Kb[6][256], Kc[6][256];
    __shared__ float Sa[1024], Sb[256], Sc[256];
    __shared__ float N0s[256], N1s[256];
    __shared__ float Pq[2][1024];

    const int tid = threadIdx.x;
    const int row = tid >> 5, col = tid & 31;
    const float dt = tarr[1] - tarr[0];

    sA[tid] = A[tid];
    if (tid < 256) { Kb[0][tid] = B[tid]; Kc[0][tid] = 0.f; }
    __syncthreads();
    Ka[0][tid] = sA[tid];
    __syncthreads();

    constexpr float atab[5][5] = {
        {0.2f, 0.f, 0.f, 0.f, 0.f},
        {3.f / 40.f, 9.f / 40.f, 0.f, 0.f, 0.f},
        {44.f / 45.f, -56.f / 15.f, 32.f / 9.f, 0.f, 0.f},
        {19372.f / 6561.f, -25360.f / 2187.f, 64448.f / 6561.f, -212.f / 729.f, 0.f},
        {9017.f / 3168.f, -355.f / 33.f, 46732.f / 5247.f, 49.f / 176.f, -5103.f / 18656.f}};
    constexpr float ctab[6] = {0.f, 0.2f, 0.3f, 0.8f, 8.f / 9.f, 1.f};

#pragma unroll
    for (int st = 1; st <= 5; ++st) {
        {
            float acc = 0.f;
#pragma unroll
            for (int j = 0; j < 5; ++j)
                if (j < st) acc += atab[st - 1][j] * Ka[j][tid];
            Sa[tid] = acc;
        }
        if (tid < 256) {
            float ab = 0.f, ac = 0.f;
#pragma unroll
            for (int j = 0; j < 5; ++j)
                if (j < st) {
                    ab += atab[st - 1][j] * Kb[j][tid];
                    ac += atab[st - 1][j] * Kc[j][tid];
                }
            Sb[tid] = ab; Sc[tid] = ac;
        }
        __syncthreads();
        {
            float acc = 0.f;
#pragma unroll
            for (int k = 0; k < NS; ++k) acc += sA[row * NS + k] * Sa[k * NS + col];
            Ka[st][tid] = sA[tid] + dt * acc;
        }
        if (tid < 256) {
            const int rb = tid >> 3, jb = tid & 7;
            float ab = 0.f, ac = 0.f;
#pragma unroll
            for (int k = 0; k < NS; ++k) {
                ab += sA[rb * NS + k] * Sb[k * NI + jb];
                ac += sA[rb * NS + k] * Sc[k * NI + jb];
            }
            Kb[st][tid] = Kb[0][tid] + dt * ab;
            Kc[st][tid] = ctab[st] * Kb[0][tid] + dt * ac;
        }
        __syncthreads();
    }

    constexpr float btab[6] = {35.f / 384.f, 0.f, 500.f / 1113.f, 125.f / 192.f,
                               -2187.f / 6784.f, 11.f / 84.f};
    {
        float acc = 0.f;
#pragma unroll
        for (int i2 = 0; i2 < 6; ++i2) acc += btab[i2] * Ka[i2][tid];
        const float m = dt * acc + ((row == col) ? 1.f : 0.f);
        ws[WS_M + tid] = m;
        MP[1][tid] = m;
        MP[0][tid] = (row == col) ? 1.f : 0.f;
    }
    if (tid < 256) {
        float ap = 0.f, aq = 0.f;
#pragma unroll
        for (int i2 = 0; i2 < 6; ++i2) {
            ap += btab[i2] * Kb[i2][tid];
            aq += btab[i2] * Kc[i2][tid];
        }
        const float P = dt * ap, Q = dt * aq;
        ws[WS_N0 + tid] = P - Q;
        ws[WS_N1 + tid] = Q;
        N0s[tid] = P - Q;
        N1s[tid] = Q;
    }
    __syncthreads();

    // M^p chain, p=2..16 (all LDS)
    for (int p = 2; p <= 16; ++p) {
        float acc = 0.f;
#pragma unroll
        for (int k = 0; k < NS; ++k) acc += MP[1][row * NS + k] * MP[p - 1][k * NS + col];
        MP[p][tid] = acc;
        __syncthreads();
    }

    // PK[k] = (M^16)^k
    ws[WS_PK + tid] = MP[0][tid];
    ws[WS_PK + 1024 + tid] = MP[16][tid];
    Pq[0][tid] = MP[16][tid];
    __syncthreads();
    int cur = 0;
    for (int k3 = 2; k3 <= 16; ++k3) {
        float acc = 0.f;
#pragma unroll
        for (int k = 0; k < NS; ++k) acc += Pq[cur][row * NS + k] * MP[16][k * NS + col];
        Pq[cur ^ 1][tid] = acc;
        __syncthreads();
        cur ^= 1;
        ws[WS_PK + k3 * 1024 + tid] = acc;
    }

    // W_j = (j<=15 ? M^{15-j} N0 : 0) + (j>=1 ? M^{16-j} N1 : 0), j=0..16
    for (int idx = tid; idx < 17 * 256; idx += 1024) {
        const int j = idx >> 8, e = idx & 255;
        const int r = e >> 3, cc = e & 7;
        float acc = 0.f;
        if (j <= 15) {
            const float* Mp = &MP[15 - j][r * NS];
#pragma unroll
            for (int k = 0; k < NS; ++k) acc += Mp[k] * N0s[k * NI + cc];
        }
        if (j >= 1) {
            const float* Mp = &MP[16 - j][r * NS];
#pragma unroll
            for (int k = 0; k < NS; ++k) acc += Mp[k] * N1s[k * NI + cc];
        }
        ws[WS_W + idx] = acc;
    }
}

// ---------------------------------------------------------------------------
// k_v: v[b][c] = sum_{j=0}^{16} W_j u[b][16c+j], one thread per (b,c).
// ---------------------------------------------------------------------------
__global__ __launch_bounds__(64) void k_v(const float* __restrict__ u,
                                          float* __restrict__ ws) {
    __shared__ __align__(16) float Wld[17 * 256];
    const int l = threadIdx.x;
    for (int i = l; i < 17 * 256; i += 64) Wld[i] = ws[WS_W + i];
    __syncthreads();

    const int b = blockIdx.x >> 2;
    const int c = ((blockIdx.x & 3) << 6) + l;
    if (c >= NCH - 1) return;

    float acc[NS];
#pragma unroll
    for (int r = 0; r < NS; ++r) acc[r] = 0.f;

    const float* ub = u + ((size_t)b * TT + (size_t)c * LCH) * NI;
    for (int j = 0; j <= 16; ++j) {
        const float4 ua = ld4(ub + j * NI);
        const float4 ub4 = ld4(ub + j * NI + 4);
        const float4* wj = (const float4*)(Wld + j * 256);
#pragma unroll
        for (int r = 0; r < NS; ++r)
            acc[r] += dot4(wj[2 * r], ua) + dot4(wj[2 * r + 1], ub4);
    }
    float* vout = ws + WS_V + ((size_t)b * NCH + c) * NS;
#pragma unroll
    for (int r8 = 0; r8 < 8; ++r8)
        *(float4*)(vout + 4 * r8) =
            make_float4(acc[4 * r8], acc[4 * r8 + 1], acc[4 * r8 + 2], acc[4 * r8 + 3]);
}

// ---------------------------------------------------------------------------
// k_scan2a: per (b,S): r_0=0; r_k = ML16 r_{k-1} + v[16S+k-1]; store in-place.
// ---------------------------------------------------------------------------
__global__ __launch_bounds__(64) void k_scan2a(float* __restrict__ ws) {
    const int b = blockIdx.x >> 4, S = blockIdx.x & 15;
    const int l = threadIdx.x, i = l & 31, h = l >> 5;
    const float* pk1 = ws + WS_PK + 1024;
    float mlr[16];
#pragma unroll
    for (int jj = 0; jj < 16; ++jj) mlr[jj] = pk1[i * NS + 16 * h + jj];

    float r = 0.f;
    for (int k = 1; k <= 16; ++k) {
        if (k == 16 && S == 15) break;
        const int slot = (S << 4) + k - 1;
        float p = 0.f;
#pragma unroll
        for (int jj = 0; jj < 16; ++jj) p += mlr[jj] * __shfl(r, 16 * h + jj, 64);
        p += __shfl_xor(p, 32, 64);
        float vv = 0.f;
        if (h == 0) vv = ws[WS_V + ((size_t)b * NCH + slot) * NS + i];
        r = p + vv;
        if (h == 0) {
            if (k < 16)
                ws[WS_V + ((size_t)b * NCH + slot) * NS + i] = r;
            else
                ws[WS_VV + ((size_t)(b << 4) + S) * NS + i] = r;
        }
    }
}

// ---------------------------------------------------------------------------
// k_scan2b: ssup[b][0]=x0[b]; ssup[b][S+1] = ML256 ssup[b][S] + VV[b][S].
// ---------------------------------------------------------------------------
__global__ __launch_bounds__(64) void k_scan2b(const float* __restrict__ x0,
                                               float* __restrict__ ws) {
    const int b = blockIdx.x;
    const int l = threadIdx.x, i = l & 31, h = l >> 5;
    const float* mlp = ws + WS_PK + 16 * 1024;
    float mlr[16];
#pragma unroll
    for (int jj = 0; jj < 16; ++jj) mlr[jj] = mlp[i * NS + 16 * h + jj];

    float x = x0[b * NS + i];
    for (int S = 0; S < NSUP; ++S) {
        if (h == 0) ws[WS_SS + ((size_t)(b << 4) + S) * NS + i] = x;
        if (S == NSUP - 1) break;
        float p = 0.f;
#pragma unroll
        for (int jj = 0; jj < 16; ++jj) p += mlr[jj] * __shfl(x, 16 * h + jj, 64);
        p += __shfl_xor(p, 32, 64);
        float vv = 0.f;
        if (h == 0) vv = ws[WS_VV + ((size_t)(b << 4) + S) * NS + i];
        x = p + vv;
    }
}

// ---------------------------------------------------------------------------
// k_phase3: per (b,c) replay 16 steps from s = PK[k] ssup[b][S] + r[b][c-1],
// writing xs and ys. 256-thread blocks = 4 INDEPENDENT waves (no barriers;
// all LDS dependencies are intra-wave and handled by lgkmcnt).
// Wave = 8 tasks (8 consecutive b, same c); 8 lanes/task, 4 rows/lane.
// ---------------------------------------------------------------------------
__global__ __launch_bounds__(256, 2) void k_phase3(const float* __restrict__ u,
                                                   float* __restrict__ ws,
                                                   float* __restrict__ out,
                                                   const float* __restrict__ Cc,
                                                   const float* __restrict__ Dd) {
    const int wv = threadIdx.x >> 6, l = threadIdx.x & 63;
    const int Wid = blockIdx.x * 4 + wv;
    const int c = Wid & 255, g = Wid >> 8;
    const int beta = l >> 3, s8 = l & 7;
    const int b = g * 8 + beta;
    const int S = c >> 4, k = c & 15;
    const int t0 = c * LCH;

    __shared__ float4 uld[4][8 * 34];
    __shared__ float4 yld[4][8 * 34];
    __shared__ float4 xb[4][2][8 * 9];

    // stage u: 32 f4 per task (16 samples x 8 floats)
    const float4* u4 = (const float4*)u;
    for (int f = l; f < 8 * 32; f += 64) {
        const int task = f >> 5, e = f & 31;
        uld[wv][task * 34 + e] = u4[((size_t)(g * 8 + task) * TT + t0) * 2 + e];
    }

    // start state: s = PK[k] @ ssup[b][S] + (k ? r[b][c-1] : 0)
    float4 mine;
    {
        const float* pk = ws + WS_PK + k * 1024;
        const float* ss = ws + WS_SS + ((size_t)(b << 4) + S) * NS;
        float a0 = 0.f, a1 = 0.f, a2 = 0.f, a3 = 0.f;
#pragma unroll
        for (int jj = 0; jj < 8; ++jj) {
            const float4 sv = ld4(ss + 4 * jj);
            a0 += dot4(ld4(pk + (4 * s8 + 0) * NS + 4 * jj), sv);
            a1 += dot4(ld4(pk + (4 * s8 + 1) * NS + 4 * jj), sv);
            a2 += dot4(ld4(pk + (4 * s8 + 2) * NS + 4 * jj), sv);
            a3 += dot4(ld4(pk + (4 * s8 + 3) * NS + 4 * jj), sv);
        }
        if (k) {
            const float4 rv = ld4(ws + WS_V + ((size_t)b * NCH + c - 1) * NS + 4 * s8);
            a0 += rv.x; a1 += rv.y; a2 += rv.z; a3 += rv.w;
        }
        mine = make_float4(a0, a1, a2, a3);
    }

    // fragment caches
    const float* M = ws + WS_M;
    const float* N0 = ws + WS_N0;
    const float* N1 = ws + WS_N1;
    float4 mq[4][8];
#pragma unroll
    for (int r = 0; r < 4; ++r)
#pragma unroll
        for (int jj = 0; jj < 8; ++jj) mq[r][jj] = ld4(M + (4 * s8 + r) * NS + 4 * jj);
    float4 n0q[4][2], n1q[4][2];
#pragma unroll
    for (int r = 0; r < 4; ++r) {
        n0q[r][0] = ld4(N0 + (4 * s8 + r) * NI);
        n0q[r][1] = ld4(N0 + (4 * s8 + r) * NI + 4);
        n1q[r][0] = ld4(N1 + (4 * s8 + r) * NI);
        n1q[r][1] = ld4(N1 + (4 * s8 + r) * NI + 4);
    }
    float4 cq[8], dq0, dq1;
#pragma unroll
    for (int jj = 0; jj < 8; ++jj) cq[jj] = ld4(Cc + s8 * NS + 4 * jj);
    dq0 = ld4(Dd + s8 * NI);
    dq1 = ld4(Dd + s8 * NI + 4);

    xb[wv][0][beta * 9 + s8] = mine;

    float* outx = out + ((size_t)b * TT + t0) * NS + 4 * s8;
    float* ybuf = (float*)&yld[wv][beta * 34];

    int cur = 0;
#pragma unroll 2
    for (int js = 0; js < LCH; ++js) {
        // xs store (streaming; no forced drain — no barrier in this loop)
        *(float4*)outx = mine;
        outx += NS;

        const bool upd = js < LCH - 1;
        const float4 u0a = uld[wv][beta * 34 + 2 * js];
        const float4 u0b = uld[wv][beta * 34 + 2 * js + 1];
        const int jn = upd ? 2 * js + 2 : 2 * js;
        const float4 u1a = uld[wv][jn == 2 * js ? beta * 34 + jn : beta * 34 + jn];
        const float4 u1b = uld[wv][beta * 34 + jn + 1];

        float w0 = dot4(n0q[0][0], u0a) + dot4(n0q[0][1], u0b) + dot4(n1q[0][0], u1a) + dot4(n1q[0][1], u1b);
        float w1 = dot4(n0q[1][0], u0a) + dot4(n0q[1][1], u0b) + dot4(n1q[1][0], u1a) + dot4(n1q[1][1], u1b);
        float w2 = dot4(n0q[2][0], u0a) + dot4(n0q[2][1], u0b) + dot4(n1q[2][0], u1a) + dot4(n1q[2][1], u1b);
        float w3 = dot4(n0q[3][0], u0a) + dot4(n0q[3][1], u0b) + dot4(n1q[3][0], u1a) + dot4(n1q[3][1], u1b);
        float yv = dot4(dq0, u0a) + dot4(dq1, u0b);

#pragma unroll
        for (int jj = 0; jj < 8; ++jj) {
            const float4 xv = xb[wv][cur][beta * 9 + jj];
            yv += dot4(cq[jj], xv);
            w0 += dot4(mq[0][jj], xv);
            w1 += dot4(mq[1][jj], xv);
            w2 += dot4(mq[2][jj], xv);
            w3 += dot4(mq[3][jj], xv);
        }
        ybuf[js * NO + s8] = yv;

        if (upd) {
            mine = make_float4(w0, w1, w2, w3);
            xb[wv][cur ^ 1][beta * 9 + s8] = mine;
        }
        cur ^= 1;
    }

    // coalesced y writeout: 32 f4 per task
    float* yout = out + (size_t)BATCH * TT * NS;
    float4* ybase = (float4*)(yout + ((size_t)b * TT + t0) * NO);
#pragma unroll
    for (int q = 0; q < 4; ++q) ybase[s8 * 4 + q] = yld[wv][beta * 34 + s8 * 4 + q];
}

extern "C" void kernel_launch(void* const* d_in, const int* in_sizes, int n_in,
                              void* d_out, int out_size, void* d_ws, size_t ws_size,
                              hipStream_t stream) {
    const float* t = (const float*)d_in[0];
    const float* u = (const float*)d_in[1];
    const float* x0 = (const float*)d_in[2];
    const float* A = (const float*)d_in[3];
    const float* B = (const float*)d_in[4];
    const float* C = (const float*)d_in[5];
    const float* D = (const float*)d_in[6];
    float* out = (float*)d_out;
    float* ws = (float*)d_ws;

    k_pre<<<dim3(1), dim3(1024), 0, stream>>>(t, A, B, ws);
    k_v<<<dim3(BATCH * 4), dim3(64), 0, stream>>>(u, ws);
    k_scan2a<<<dim3(BATCH * NSUP), dim3(64), 0, stream>>>(ws);
    k_scan2b<<<dim3(BATCH), dim3(64), 0, stream>>>(x0, ws);
    k_phase3<<<dim3(2048), dim3(256), 0, stream>>>(u, ws, out, C, D);
}